// Round 1
// baseline (51958.545 us; speedup 1.0000x reference)
//
#include <hip/hip_runtime.h>
#include <hip/hip_bf16.h>
#include <cstddef>

#define NN 100000
#define EE 3200000

// ---------- helpers ----------

__device__ __forceinline__ float wsum(float v) {
  #pragma unroll
  for (int off = 32; off > 0; off >>= 1) v += __shfl_down(v, off, 64);
  return v;  // lane 0 holds wave total
}

template<int K>
__device__ __forceinline__ void matAccK(const float* in, const float* sw, float y[32]) {
  #pragma unroll
  for (int k = 0; k < K; k++) {
    const float v = in[k];
    #pragma unroll
    for (int j = 0; j < 32; j++) y[j] = fmaf(v, sw[k * 32 + j], y[j]);
  }
}

template<int K>
__device__ __forceinline__ void matK(const float* in, const float* sw, const float* sb, float y[32]) {
  #pragma unroll
  for (int j = 0; j < 32; j++) y[j] = sb[j];
  matAccK<K>(in, sw, y);
}

__device__ __forceinline__ void load_in13(const float* __restrict__ x, const float* __restrict__ c10,
                                          const float* __restrict__ ea, int s, int e, float in[13]) {
  #pragma unroll
  for (int k = 0; k < 10; k++) in[k] = x[(size_t)s * 11 + k];
  in[10] = c10[s];
  const float2 e2 = reinterpret_cast<const float2*>(ea)[e];
  in[11] = e2.x; in[12] = e2.y;
}

// block-level reduce of 32 sums + 32 sumsq -> global atomics. red = shared float[256].
__device__ __forceinline__ void reduce64(float sum[32], float ssq[32], float* red,
                                         float* __restrict__ gsum, float* __restrict__ gssq) {
  const int wid = threadIdx.x >> 6, lane = threadIdx.x & 63;
  #pragma unroll
  for (int j = 0; j < 32; j++) {
    float a = wsum(sum[j]);
    float b = wsum(ssq[j]);
    if (lane == 0) { red[wid * 64 + j] = a; red[wid * 64 + 32 + j] = b; }
  }
  __syncthreads();
  if (threadIdx.x < 64) {
    float t = red[threadIdx.x] + red[64 + threadIdx.x] + red[128 + threadIdx.x] + red[192 + threadIdx.x];
    if (threadIdx.x < 32) unsafeAtomicAdd(&gsum[threadIdx.x], t);
    else                  unsafeAtomicAdd(&gssq[threadIdx.x - 32], t);
  }
}

// ---------- CSR build (dst constant across convs; built once per launch) ----------

__global__ __launch_bounds__(256) void k_count(const int* __restrict__ dst, int* __restrict__ cnt) {
  int e = blockIdx.x * 256 + threadIdx.x, S = gridDim.x * 256;
  for (; e < EE; e += S) atomicAdd(&cnt[dst[e]], 1);
}

__global__ __launch_bounds__(1024) void k_scan(const int* __restrict__ cnt,
                                               int* __restrict__ starts, int* __restrict__ fill) {
  __shared__ int part[1024];
  const int T = 1024, CH = (NN + T - 1) / T;
  int t = threadIdx.x;
  int lo = t * CH, hi = min(lo + CH, NN);
  int s = 0;
  for (int i = lo; i < hi; i++) s += cnt[i];
  part[t] = s; __syncthreads();
  for (int off = 1; off < T; off <<= 1) {
    int v = (t >= off) ? part[t - off] : 0;
    __syncthreads();
    part[t] += v;
    __syncthreads();
  }
  int run = part[t] - s;  // exclusive prefix
  for (int i = lo; i < hi; i++) { starts[i] = run; fill[i] = run; run += cnt[i]; }
  if (t == T - 1) starts[NN] = EE;
}

__global__ __launch_bounds__(256) void k_scatter(const int* __restrict__ dst,
                                                 int* __restrict__ fill, int* __restrict__ csr) {
  int e = blockIdx.x * 256 + threadIdx.x, S = gridDim.x * 256;
  for (; e < EE; e += S) { int p = atomicAdd(&fill[dst[e]], 1); csr[p] = e; }
}

__global__ __launch_bounds__(256) void k_extract(const float* __restrict__ x, float* __restrict__ c10) {
  int n = blockIdx.x * 256 + threadIdx.x;
  if (n < NN) c10[n] = x[(size_t)n * 11 + 10];
}

// ---------- BN finalize: a = g*rsqrt(var+eps), c = be - mu*a; zero sums for reuse ----------

__global__ void k_finalize(float* __restrict__ sum, float* __restrict__ ssq,
                           const float* __restrict__ g, const float* __restrict__ be,
                           float inv_n, int ncols, float* __restrict__ a, float* __restrict__ c) {
  int j = threadIdx.x;
  if (j < ncols) {
    float mu = sum[j] * inv_n;
    float var = fmaxf(ssq[j] * inv_n - mu * mu, 0.f);
    float s = rsqrtf(var + 1e-5f) * g[j];
    a[j] = s; c[j] = be[j] - mu * s;
    sum[j] = 0.f; ssq[j] = 0.f;
  }
}

// ---------- P1: stats of y1 = [x_src, ea] @ w1a + b1a over E ----------

__global__ __launch_bounds__(256) void k_p1(const float* __restrict__ x, const float* __restrict__ c10,
    const float* __restrict__ ea, const int* __restrict__ src,
    const float* __restrict__ w1a, const float* __restrict__ b1a,
    float* __restrict__ gsum, float* __restrict__ gssq) {
  __shared__ float sw[13 * 32], sb[32], red[256];
  for (int i = threadIdx.x; i < 13 * 32; i += 256) sw[i] = w1a[i];
  if (threadIdx.x < 32) sb[threadIdx.x] = b1a[threadIdx.x];
  __syncthreads();
  float sum[32], ssq[32];
  #pragma unroll
  for (int j = 0; j < 32; j++) { sum[j] = 0.f; ssq[j] = 0.f; }
  const int S = gridDim.x * 256;
  for (int e = blockIdx.x * 256 + threadIdx.x; e < EE; e += S) {
    float in[13], y[32];
    load_in13(x, c10, ea, src[e], e, in);
    matK<13>(in, sw, sb, y);
    #pragma unroll
    for (int j = 0; j < 32; j++) { sum[j] += y[j]; ssq[j] = fmaf(y[j], y[j], ssq[j]); }
  }
  reduce64(sum, ssq, red, gsum, gssq);
}

// ---------- P2: stats of y2 = relu(bn(y1)) @ w1b + b1b over E ----------

__global__ __launch_bounds__(256) void k_p2(const float* __restrict__ x, const float* __restrict__ c10,
    const float* __restrict__ ea, const int* __restrict__ src,
    const float* __restrict__ w1a, const float* __restrict__ b1a,
    const float* __restrict__ a1, const float* __restrict__ c1,
    const float* __restrict__ w1b, const float* __restrict__ b1b,
    float* __restrict__ gsum, float* __restrict__ gssq) {
  __shared__ float sw1[13 * 32], sw2[32 * 32], sb1[32], sa1[32], sc1[32], sb2[32], red[256];
  for (int i = threadIdx.x; i < 13 * 32; i += 256) sw1[i] = w1a[i];
  for (int i = threadIdx.x; i < 32 * 32; i += 256) sw2[i] = w1b[i];
  if (threadIdx.x < 32) {
    int t = threadIdx.x;
    sb1[t] = b1a[t]; sa1[t] = a1[t]; sc1[t] = c1[t]; sb2[t] = b1b[t];
  }
  __syncthreads();
  float sum[32], ssq[32];
  #pragma unroll
  for (int j = 0; j < 32; j++) { sum[j] = 0.f; ssq[j] = 0.f; }
  const int S = gridDim.x * 256;
  for (int e = blockIdx.x * 256 + threadIdx.x; e < EE; e += S) {
    float in[13], y[32], m[32], z[32];
    load_in13(x, c10, ea, src[e], e, in);
    matK<13>(in, sw1, sb1, y);
    #pragma unroll
    for (int j = 0; j < 32; j++) m[j] = fmaxf(0.f, fmaf(y[j], sa1[j], sc1[j]));
    matK<32>(m, sw2, sb2, z);
    #pragma unroll
    for (int j = 0; j < 32; j++) { sum[j] += z[j]; ssq[j] = fmaf(z[j], z[j], ssq[j]); }
  }
  reduce64(sum, ssq, red, gsum, gssq);
}

// ---------- P3a: node-centric max aggregation (4 threads per node, no atomics) ----------

__global__ __launch_bounds__(256) void k_agg(const int* __restrict__ starts, const int* __restrict__ csr,
    const int* __restrict__ src, const float* __restrict__ x, const float* __restrict__ c10,
    const float* __restrict__ ea,
    const float* __restrict__ w1a, const float* __restrict__ b1a,
    const float* __restrict__ a1, const float* __restrict__ c1,
    const float* __restrict__ w1b, const float* __restrict__ b1b,
    const float* __restrict__ a2, const float* __restrict__ c2,
    float* __restrict__ agg) {
  __shared__ float sw1[13 * 32], sw2[32 * 32], sb1[32], sa1[32], sc1[32], sb2[32], sa2[32], sc2[32];
  for (int i = threadIdx.x; i < 13 * 32; i += 256) sw1[i] = w1a[i];
  for (int i = threadIdx.x; i < 32 * 32; i += 256) sw2[i] = w1b[i];
  if (threadIdx.x < 32) {
    int t = threadIdx.x;
    sb1[t] = b1a[t]; sa1[t] = a1[t]; sc1[t] = c1[t];
    sb2[t] = b1b[t]; sa2[t] = a2[t]; sc2[t] = c2[t];
  }
  __syncthreads();
  const int t = blockIdx.x * 256 + threadIdx.x;
  const int n = t >> 2, q = t & 3;
  float mx[32];
  #pragma unroll
  for (int j = 0; j < 32; j++) mx[j] = 0.f;   // exact: post-relu >= 0, empty segment -> 0
  if (n < NN) {
    const int lo = starts[n], hi = starts[n + 1];
    for (int sl = lo + q; sl < hi; sl += 4) {
      const int e = csr[sl];
      float in[13], y[32], m[32], z[32];
      load_in13(x, c10, ea, src[e], e, in);
      matK<13>(in, sw1, sb1, y);
      #pragma unroll
      for (int j = 0; j < 32; j++) m[j] = fmaxf(0.f, fmaf(y[j], sa1[j], sc1[j]));
      matK<32>(m, sw2, sb2, z);
      #pragma unroll
      for (int j = 0; j < 32; j++) {
        float m2 = fmaxf(0.f, fmaf(z[j], sa2[j], sc2[j]));
        mx[j] = fmaxf(mx[j], m2);
      }
    }
  }
  // combine 4 partial maxes (lanes 4n..4n+3 are in the same wave; 64 % 4 == 0)
  #pragma unroll
  for (int j = 0; j < 32; j++) {
    mx[j] = fmaxf(mx[j], __shfl_xor(mx[j], 1, 64));
    mx[j] = fmaxf(mx[j], __shfl_xor(mx[j], 2, 64));
  }
  if (q == 0 && n < NN) {
    float4* out = reinterpret_cast<float4*>(agg + (size_t)n * 32);
    #pragma unroll
    for (int j = 0; j < 8; j++)
      out[j] = make_float4(mx[4 * j], mx[4 * j + 1], mx[4 * j + 2], mx[4 * j + 3]);
  }
}

// ---------- P3b: h_pre = [x, agg] @ w2a + b2a, store + stats over N ----------

__global__ __launch_bounds__(256) void k_hpre(const float* __restrict__ x, const float* __restrict__ c10,
    const float* __restrict__ agg, const float* __restrict__ w2a, const float* __restrict__ b2a,
    float* __restrict__ hpre, float* __restrict__ gsum, float* __restrict__ gssq) {
  __shared__ float sw[43 * 32], sb[32], red[256];
  for (int i = threadIdx.x; i < 43 * 32; i += 256) sw[i] = w2a[i];
  if (threadIdx.x < 32) sb[threadIdx.x] = b2a[threadIdx.x];
  __syncthreads();
  float sum[32], ssq[32];
  #pragma unroll
  for (int j = 0; j < 32; j++) { sum[j] = 0.f; ssq[j] = 0.f; }
  const int S = gridDim.x * 256;
  for (int n = blockIdx.x * 256 + threadIdx.x; n < NN; n += S) {
    float in0[11], h[32], av[32];
    #pragma unroll
    for (int k = 0; k < 10; k++) in0[k] = x[(size_t)n * 11 + k];
    in0[10] = c10[n];
    const float4* ag = reinterpret_cast<const float4*>(agg + (size_t)n * 32);
    #pragma unroll
    for (int j = 0; j < 8; j++) {
      float4 v = ag[j];
      av[4 * j] = v.x; av[4 * j + 1] = v.y; av[4 * j + 2] = v.z; av[4 * j + 3] = v.w;
    }
    matK<11>(in0, sw, sb, h);
    matAccK<32>(av, sw + 11 * 32, h);
    float4* hp = reinterpret_cast<float4*>(hpre + (size_t)n * 32);
    #pragma unroll
    for (int j = 0; j < 8; j++)
      hp[j] = make_float4(h[4 * j], h[4 * j + 1], h[4 * j + 2], h[4 * j + 3]);
    #pragma unroll
    for (int j = 0; j < 32; j++) { sum[j] += h[j]; ssq[j] = fmaf(h[j], h[j], ssq[j]); }
  }
  reduce64(sum, ssq, red, gsum, gssq);
}

// ---------- P4: comb = relu(relu(bn(h_pre)) @ w2b + b2b) -> new col10 ----------

__global__ __launch_bounds__(256) void k_comb(const float* __restrict__ hpre,
    const float* __restrict__ a3, const float* __restrict__ c3,
    const float* __restrict__ w2b, const float* __restrict__ b2b, float* __restrict__ out10) {
  __shared__ float sw[32], sa[32], sc[32];
  if (threadIdx.x < 32) {
    int t = threadIdx.x;
    sw[t] = w2b[t]; sa[t] = a3[t]; sc[t] = c3[t];
  }
  __syncthreads();
  int n = blockIdx.x * 256 + threadIdx.x;
  if (n >= NN) return;
  const float4* hp = reinterpret_cast<const float4*>(hpre + (size_t)n * 32);
  float acc = b2b[0];
  #pragma unroll
  for (int j = 0; j < 8; j++) {
    float4 v = hp[j];
    acc += fmaxf(0.f, fmaf(v.x, sa[4 * j],     sc[4 * j]))     * sw[4 * j];
    acc += fmaxf(0.f, fmaf(v.y, sa[4 * j + 1], sc[4 * j + 1])) * sw[4 * j + 1];
    acc += fmaxf(0.f, fmaf(v.z, sa[4 * j + 2], sc[4 * j + 2])) * sw[4 * j + 2];
    acc += fmaxf(0.f, fmaf(v.w, sa[4 * j + 3], sc[4 * j + 3])) * sw[4 * j + 3];
  }
  out10[n] = fmaxf(acc, 0.f);
}

// ---------- P5: stats of yp = x @ wpa + bpa over N ----------

__global__ __launch_bounds__(256) void k_p5(const float* __restrict__ x, const float* __restrict__ c10,
    const float* __restrict__ wpa, const float* __restrict__ bpa,
    float* __restrict__ gsum, float* __restrict__ gssq) {
  __shared__ float sw[11 * 32], sb[32], red[256];
  for (int i = threadIdx.x; i < 11 * 32; i += 256) sw[i] = wpa[i];
  if (threadIdx.x < 32) sb[threadIdx.x] = bpa[threadIdx.x];
  __syncthreads();
  float sum[32], ssq[32];
  #pragma unroll
  for (int j = 0; j < 32; j++) { sum[j] = 0.f; ssq[j] = 0.f; }
  const int S = gridDim.x * 256;
  for (int n = blockIdx.x * 256 + threadIdx.x; n < NN; n += S) {
    float in0[11], y[32];
    #pragma unroll
    for (int k = 0; k < 10; k++) in0[k] = x[(size_t)n * 11 + k];
    in0[10] = c10[n];
    matK<11>(in0, sw, sb, y);
    #pragma unroll
    for (int j = 0; j < 32; j++) { sum[j] += y[j]; ssq[j] = fmaf(y[j], y[j], ssq[j]); }
  }
  reduce64(sum, ssq, red, gsum, gssq);
}

// ---------- P6: yq = relu(bn(yp)) @ wpb + bpb, store + scalar stats ----------

__global__ __launch_bounds__(256) void k_p6(const float* __restrict__ x, const float* __restrict__ c10,
    const float* __restrict__ wpa, const float* __restrict__ bpa,
    const float* __restrict__ a4, const float* __restrict__ c4,
    const float* __restrict__ wpb, const float* __restrict__ bpb,
    float* __restrict__ yq, float* __restrict__ gsum, float* __restrict__ gssq) {
  __shared__ float sw[11 * 32], sb[32], sa[32], sc[32], swb[32], red[8];
  for (int i = threadIdx.x; i < 11 * 32; i += 256) sw[i] = wpa[i];
  if (threadIdx.x < 32) {
    int t = threadIdx.x;
    sb[t] = bpa[t]; sa[t] = a4[t]; sc[t] = c4[t]; swb[t] = wpb[t];
  }
  __syncthreads();
  float sum = 0.f, ssq = 0.f;
  const int S = gridDim.x * 256;
  for (int n = blockIdx.x * 256 + threadIdx.x; n < NN; n += S) {
    float in0[11], y[32];
    #pragma unroll
    for (int k = 0; k < 10; k++) in0[k] = x[(size_t)n * 11 + k];
    in0[10] = c10[n];
    matK<11>(in0, sw, sb, y);
    float q = bpb[0];
    #pragma unroll
    for (int j = 0; j < 32; j++) q += fmaxf(0.f, fmaf(y[j], sa[j], sc[j])) * swb[j];
    yq[n] = q;
    sum += q; ssq = fmaf(q, q, ssq);
  }
  float s = wsum(sum), qq = wsum(ssq);
  const int wid = threadIdx.x >> 6, lane = threadIdx.x & 63;
  if (lane == 0) { red[wid] = s; red[4 + wid] = qq; }
  __syncthreads();
  if (threadIdx.x == 0) {
    unsafeAtomicAdd(&gsum[0], red[0] + red[1] + red[2] + red[3]);
    unsafeAtomicAdd(&gssq[0], red[4] + red[5] + red[6] + red[7]);
  }
}

// ---------- P7: out = relu(bn(yq)) ----------

__global__ __launch_bounds__(256) void k_p7(const float* __restrict__ yq,
    const float* __restrict__ a5, const float* __restrict__ c5, float* __restrict__ out) {
  int n = blockIdx.x * 256 + threadIdx.x;
  if (n < NN) out[n] = fmaxf(0.f, fmaf(yq[n], a5[0], c5[0]));
}

// ---------- host launch ----------

extern "C" void kernel_launch(void* const* d_in, const int* in_sizes, int n_in,
                              void* d_out, int out_size, void* d_ws, size_t ws_size,
                              hipStream_t stream) {
  const float* x    = (const float*)d_in[0];
  const float* ea   = (const float*)d_in[1];
  const int*   ei   = (const int*)d_in[2];
  const int*   srcp = ei;
  const int*   dstp = ei + EE;
  const float* w1a = (const float*)d_in[3],  *b1a = (const float*)d_in[4];
  const float* g1a = (const float*)d_in[5],  *be1a = (const float*)d_in[6];
  const float* w1b = (const float*)d_in[7],  *b1b = (const float*)d_in[8];
  const float* g1b = (const float*)d_in[9],  *be1b = (const float*)d_in[10];
  const float* w2a = (const float*)d_in[11], *b2a = (const float*)d_in[12];
  const float* g2a = (const float*)d_in[13], *be2a = (const float*)d_in[14];
  const float* w2b = (const float*)d_in[15], *b2b = (const float*)d_in[16];
  const float* wpa = (const float*)d_in[17], *bpa = (const float*)d_in[18];
  const float* gpa = (const float*)d_in[19], *bepa = (const float*)d_in[20];
  const float* wpb = (const float*)d_in[21], *bpb = (const float*)d_in[22];
  const float* gpb = (const float*)d_in[23], *bepb = (const float*)d_in[24];

  size_t off = 0;
  char* base = (char*)d_ws;
  auto alloc = [&](size_t bytes) -> void* {
    void* p = base + off;
    off += (bytes + 255) & ~(size_t)255;
    return p;
  };
  float* stats = (float*)alloc(2048);              // 512 floats of sums/ssqs
  float* coef  = (float*)alloc(2048);
  int* cnt    = (int*)alloc(NN * 4);
  int* starts = (int*)alloc((NN + 1) * 4);
  int* fill   = (int*)alloc(NN * 4);
  int* csr    = (int*)alloc((size_t)EE * 4);
  float* colA = (float*)alloc(NN * 4);
  float* colB = (float*)alloc(NN * 4);
  float* agg  = (float*)alloc((size_t)NN * 32 * 4);
  float* hpre = (float*)alloc((size_t)NN * 32 * 4);
  float* yq   = (float*)alloc(NN * 4);

  float *SUM1 = stats, *SSQ1 = stats + 32, *SUM2 = stats + 64, *SSQ2 = stats + 96;
  float *SUM3 = stats + 128, *SSQ3 = stats + 160, *SUM4 = stats + 192, *SSQ4 = stats + 224;
  float *SUM5 = stats + 256, *SSQ5 = stats + 288;
  float *A1 = coef, *C1 = coef + 32, *A2 = coef + 64, *C2 = coef + 96;
  float *A3 = coef + 128, *C3 = coef + 160, *A4 = coef + 192, *C4 = coef + 224;
  float *A5 = coef + 256, *C5 = coef + 288;

  hipMemsetAsync(stats, 0, 2048, stream);
  hipMemsetAsync(cnt, 0, NN * 4, stream);

  const int GE = 2048;              // edge-kernel grid
  const int GN = (NN + 255) / 256;  // node-kernel grid (391)
  const int GA = (4 * NN + 255) / 256;

  k_count  <<<1024, 256, 0, stream>>>(dstp, cnt);
  k_scan   <<<1, 1024, 0, stream>>>(cnt, starts, fill);
  k_scatter<<<1024, 256, 0, stream>>>(dstp, fill, csr);
  k_extract<<<GN, 256, 0, stream>>>(x, colB);

  const float invE = 1.f / (float)EE, invN = 1.f / (float)NN;
  float* cur = colB;
  float* nxt = colA;
  for (int c = 0; c < 3; c++) {
    k_p1<<<GE, 256, 0, stream>>>(x, cur, ea, srcp, w1a, b1a, SUM1, SSQ1);
    k_finalize<<<1, 32, 0, stream>>>(SUM1, SSQ1, g1a, be1a, invE, 32, A1, C1);
    k_p2<<<GE, 256, 0, stream>>>(x, cur, ea, srcp, w1a, b1a, A1, C1, w1b, b1b, SUM2, SSQ2);
    k_finalize<<<1, 32, 0, stream>>>(SUM2, SSQ2, g1b, be1b, invE, 32, A2, C2);
    k_agg<<<GA, 256, 0, stream>>>(starts, csr, srcp, x, cur, ea,
                                  w1a, b1a, A1, C1, w1b, b1b, A2, C2, agg);
    k_hpre<<<GN, 256, 0, stream>>>(x, cur, agg, w2a, b2a, hpre, SUM3, SSQ3);
    k_finalize<<<1, 32, 0, stream>>>(SUM3, SSQ3, g2a, be2a, invN, 32, A3, C3);
    k_comb<<<GN, 256, 0, stream>>>(hpre, A3, C3, w2b, b2b, nxt);
    float* tmp = cur; cur = nxt; nxt = tmp;
  }

  k_p5<<<GN, 256, 0, stream>>>(x, cur, wpa, bpa, SUM4, SSQ4);
  k_finalize<<<1, 32, 0, stream>>>(SUM4, SSQ4, gpa, bepa, invN, 32, A4, C4);
  k_p6<<<GN, 256, 0, stream>>>(x, cur, wpa, bpa, A4, C4, wpb, bpb, yq, SUM5, SSQ5);
  k_finalize<<<1, 32, 0, stream>>>(SUM5, SSQ5, gpb, bepb, invN, 1, A5, C5);
  k_p7<<<GN, 256, 0, stream>>>(yq, A5, C5, (float*)d_out);
}

// Round 2
// 5884.545 us; speedup vs baseline: 8.8297x; 8.8297x over previous
//
#include <hip/hip_runtime.h>
#include <hip/hip_bf16.h>
#include <cstddef>

#define NN 100000
#define EE 3200000
static const float EF = 3200000.0f;

// ---------- helpers ----------

__device__ __forceinline__ float wsum(float v) {
  #pragma unroll
  for (int off = 32; off > 0; off >>= 1) v += __shfl_down(v, off, 64);
  return v;  // lane 0 holds wave total
}

// block-level reduce of 32 sums + 32 sumsq -> global atomics. red = shared float[256].
__device__ __forceinline__ void reduce64(float sum[32], float ssq[32], float* red,
                                         float* __restrict__ gsum, float* __restrict__ gssq) {
  const int wid = threadIdx.x >> 6, lane = threadIdx.x & 63;
  #pragma unroll
  for (int j = 0; j < 32; j++) {
    float a = wsum(sum[j]);
    float b = wsum(ssq[j]);
    if (lane == 0) { red[wid * 64 + j] = a; red[wid * 64 + 32 + j] = b; }
  }
  __syncthreads();
  if (threadIdx.x < 64) {
    float t = red[threadIdx.x] + red[64 + threadIdx.x] + red[128 + threadIdx.x] + red[192 + threadIdx.x];
    if (threadIdx.x < 32) unsafeAtomicAdd(&gsum[threadIdx.x], t);
    else                  unsafeAtomicAdd(&gssq[threadIdx.x - 32], t);
  }
}

// ---------- setup kernels ----------

// transpose static weights once: w2t[j][k]=w1b[k][j]; w2aT[j][0..42]+bias; wpaT[j][0..10]+bias
__global__ __launch_bounds__(256) void k_wprep(const float* __restrict__ w1b,
    const float* __restrict__ w2a, const float* __restrict__ b2a,
    const float* __restrict__ wpa, const float* __restrict__ bpa,
    float* __restrict__ w2t, float* __restrict__ w2aT, float* __restrict__ wpaT) {
  int t = threadIdx.x;
  for (int i = t; i < 1024; i += 256) { int j = i >> 5, k = i & 31; w2t[j * 32 + k] = w1b[k * 32 + j]; }
  for (int i = t; i < 32 * 43; i += 256) { int j = i & 31, k = i >> 5; w2aT[j * 44 + k] = w2a[k * 32 + j]; }
  for (int i = t; i < 32 * 11; i += 256) { int j = i & 31, k = i >> 5; wpaT[j * 12 + k] = wpa[k * 32 + j]; }
  if (t < 32) { w2aT[t * 44 + 43] = b2a[t]; wpaT[t * 12 + 11] = bpa[t]; }
}

// one edge pass: dst counts, src out-degrees, per-src edge_attr sums, global ea moments
__global__ __launch_bounds__(256) void k_prep(const int* __restrict__ dst, const int* __restrict__ src,
    const float2* __restrict__ ea, int* __restrict__ cnt, int* __restrict__ deg,
    float* __restrict__ sea, float* __restrict__ cmom) {
  float p0 = 0, p1 = 0, p2 = 0, p3 = 0, p4 = 0;
  const int S = gridDim.x * 256;
  for (int e = blockIdx.x * 256 + threadIdx.x; e < EE; e += S) {
    int d = dst[e], s = src[e];
    float2 a = ea[e];
    atomicAdd(&cnt[d], 1);
    atomicAdd(&deg[s], 1);
    unsafeAtomicAdd(&sea[2 * s], a.x);
    unsafeAtomicAdd(&sea[2 * s + 1], a.y);
    p0 += a.x * a.x; p1 += a.x * a.y; p2 += a.y * a.y; p3 += a.x; p4 += a.y;
  }
  p0 = wsum(p0); p1 = wsum(p1); p2 = wsum(p2); p3 = wsum(p3); p4 = wsum(p4);
  if ((threadIdx.x & 63) == 0) {
    unsafeAtomicAdd(&cmom[0], p0); unsafeAtomicAdd(&cmom[1], p1); unsafeAtomicAdd(&cmom[2], p2);
    unsafeAtomicAdd(&cmom[3], p3); unsafeAtomicAdd(&cmom[4], p4);
  }
}

__global__ __launch_bounds__(1024) void k_scan(const int* __restrict__ cnt,
                                               int* __restrict__ starts, int* __restrict__ fill) {
  __shared__ int part[1024];
  const int T = 1024, CH = (NN + T - 1) / T;
  int t = threadIdx.x;
  int lo = t * CH, hi = min(lo + CH, NN);
  int s = 0;
  for (int i = lo; i < hi; i++) s += cnt[i];
  part[t] = s; __syncthreads();
  for (int off = 1; off < T; off <<= 1) {
    int v = (t >= off) ? part[t - off] : 0;
    __syncthreads();
    part[t] += v;
    __syncthreads();
  }
  int run = part[t] - s;  // exclusive prefix
  for (int i = lo; i < hi; i++) { starts[i] = run; fill[i] = run; run += cnt[i]; }
  if (t == T - 1) starts[NN] = EE;
}

// scatter edges into CSR order: store src and edge_attr directly (no edge-id indirection later)
__global__ __launch_bounds__(256) void k_scatter(const int* __restrict__ dst, const int* __restrict__ src,
    const float2* __restrict__ ea, int* __restrict__ fill,
    int* __restrict__ srcc, float2* __restrict__ eac) {
  const int S = gridDim.x * 256;
  for (int e = blockIdx.x * 256 + threadIdx.x; e < EE; e += S) {
    int p = atomicAdd(&fill[dst[e]], 1);
    srcc[p] = src[e];
    eac[p] = ea[e];
  }
}

// padded node rows: xp[n][0..9]=x cols 0..9, [10]=x col10 (current), [11]=0
__global__ __launch_bounds__(256) void k_xp(const float* __restrict__ x, float* __restrict__ xp) {
  int n = blockIdx.x * 256 + threadIdx.x;
  if (n >= NN) return;
  float v[11];
  #pragma unroll
  for (int k = 0; k < 11; k++) v[k] = x[(size_t)n * 11 + k];
  float4* o = reinterpret_cast<float4*>(xp + (size_t)n * 12);
  o[0] = make_float4(v[0], v[1], v[2], v[3]);
  o[1] = make_float4(v[4], v[5], v[6], v[7]);
  o[2] = make_float4(v[8], v[9], v[10], 0.f);
}

// ---------- per-conv: input moments (node pass, replaces the P1 edge pass) ----------
// mom layout: [0..10]=S_x (deg-weighted sums), [11..76]=sxx upper-tri(11), [77..98]=sxe (x,a)x(ea,b)
__global__ __launch_bounds__(256) void k_mom(const float* __restrict__ xp, const int* __restrict__ deg,
                                             const float* __restrict__ sea, float* __restrict__ mom) {
  const int n = blockIdx.x * 256 + threadIdx.x;
  const int lane = threadIdx.x & 63;
  float v[11]; float w = 0.f; float sx = 0.f, sy = 0.f;
  #pragma unroll
  for (int k = 0; k < 11; k++) v[k] = 0.f;
  if (n < NN) {
    w = (float)deg[n];
    const float4* xr = reinterpret_cast<const float4*>(xp + (size_t)n * 12);
    float4 r0 = xr[0], r1 = xr[1], r2 = xr[2];
    v[0]=r0.x; v[1]=r0.y; v[2]=r0.z; v[3]=r0.w; v[4]=r1.x; v[5]=r1.y; v[6]=r1.z; v[7]=r1.w;
    v[8]=r2.x; v[9]=r2.y; v[10]=r2.z;
    sx = sea[2 * n]; sy = sea[2 * n + 1];
  }
  int ch = 0;
  #pragma unroll
  for (int a = 0; a < 11; a++) {
    float r = wsum(w * v[a]);
    if (lane == 0) unsafeAtomicAdd(&mom[ch], r);
    ch++;
  }
  #pragma unroll
  for (int a = 0; a < 11; a++) {
    #pragma unroll
    for (int b = a; b < 11; b++) {
      float r = wsum(w * v[a] * v[b]);
      if (lane == 0) unsafeAtomicAdd(&mom[ch], r);
      ch++;
    }
  }
  #pragma unroll
  for (int a = 0; a < 11; a++) {
    float rx = wsum(v[a] * sx);
    if (lane == 0) unsafeAtomicAdd(&mom[ch], rx);
    ch++;
    float ry = wsum(v[a] * sy);
    if (lane == 0) unsafeAtomicAdd(&mom[ch], ry);
    ch++;
  }
}

__device__ __forceinline__ float msym(const float* mom, const float* cmom, int k, int l) {
  int a = min(k, l), b = max(k, l);
  if (b < 11) return mom[11 + a * 11 - a * (a - 1) / 2 + (b - a)];
  if (a < 11) return mom[77 + a * 2 + (b - 11)];
  return cmom[(a - 11) + (b - 11)];  // (11,11)->0, (11,12)->1, (12,12)->2
}

// layer-1 BN params from moments; emit FOLDED transposed weights w1f[j][0..12]+bias[13]; zero mom.
__global__ void k_fin1(float* __restrict__ mom, const float* __restrict__ cmom,
    const float* __restrict__ w1a, const float* __restrict__ b1a,
    const float* __restrict__ g1a, const float* __restrict__ be1a,
    float* __restrict__ w1f) {
  int j = threadIdx.x;  // 32 threads
  float w[13], S[13];
  #pragma unroll
  for (int k = 0; k < 13; k++) w[k] = w1a[k * 32 + j];
  #pragma unroll
  for (int k = 0; k < 11; k++) S[k] = mom[k];
  S[11] = cmom[3]; S[12] = cmom[4];
  float lin = 0.f;
  #pragma unroll
  for (int k = 0; k < 13; k++) lin = fmaf(w[k], S[k], lin);
  float quad = 0.f;
  #pragma unroll
  for (int k = 0; k < 13; k++)
    #pragma unroll
    for (int l = 0; l < 13; l++) quad = fmaf(w[k] * w[l], msym(mom, cmom, k, l), quad);
  const float invE = 1.f / EF;
  float b = b1a[j];
  float mean = fmaf(lin, invE, b);
  float ey2 = (quad + 2.f * b * lin) * invE + b * b;
  float var = fmaxf(ey2 - mean * mean, 0.f);
  float A = g1a[j] * rsqrtf(var + 1e-5f);
  float C = be1a[j] - mean * A;
  #pragma unroll
  for (int k = 0; k < 13; k++) w1f[j * 16 + k] = A * w[k];
  w1f[j * 16 + 13] = fmaf(A, b, C);
  w1f[j * 16 + 14] = 0.f; w1f[j * 16 + 15] = 0.f;
  __syncthreads();
  for (int i = j; i < 128; i += 32) mom[i] = 0.f;
}

// ---------- the fused edge pass: MLP1 -> per-node min/max of raw z + global z stats ----------

__global__ __launch_bounds__(256) void k_fusedagg(
    const int* __restrict__ starts, const int* __restrict__ srcc, const float2* __restrict__ eac,
    const float* __restrict__ xp, const float* __restrict__ w1f, const float* __restrict__ w2t,
    const float* __restrict__ b1b,
    float* __restrict__ mxb, float* __restrict__ mnb,
    float* __restrict__ gsum, float* __restrict__ gssq) {
  __shared__ float red[256];
  const int t = blockIdx.x * 256 + threadIdx.x;
  const int n = t >> 2, q = t & 3;
  float mx[32], mn[32], zs[32], zq[32];
  #pragma unroll
  for (int j = 0; j < 32; j++) { mx[j] = -3.0e38f; mn[j] = 3.0e38f; zs[j] = 0.f; zq[j] = 0.f; }
  int lo = 0, hi = 0;
  if (n < NN) { lo = starts[n]; hi = starts[n + 1]; }
  for (int sl = lo + q; sl < hi; sl += 4) {
    const int s = srcc[sl];
    const float2 e2 = eac[sl];
    const float4* xr = reinterpret_cast<const float4*>(xp + (size_t)s * 12);
    float4 r0 = xr[0], r1 = xr[1], r2 = xr[2];
    float in[13] = {r0.x, r0.y, r0.z, r0.w, r1.x, r1.y, r1.z, r1.w, r2.x, r2.y, r2.z, e2.x, e2.y};
    float m[32];
    #pragma unroll
    for (int j = 0; j < 32; j++) {
      const float* wr = w1f + j * 16;   // uniform -> scalar loads
      float a = wr[13];
      #pragma unroll
      for (int k = 0; k < 13; k++) a = fmaf(in[k], wr[k], a);
      m[j] = fmaxf(a, 0.f);
    }
    #pragma unroll
    for (int j = 0; j < 32; j++) {
      const float* wr = w2t + j * 32;   // uniform -> scalar loads
      float z0 = b1b[j], z1 = 0.f;
      #pragma unroll
      for (int k = 0; k < 32; k += 2) { z0 = fmaf(m[k], wr[k], z0); z1 = fmaf(m[k + 1], wr[k + 1], z1); }
      float z = z0 + z1;
      mx[j] = fmaxf(mx[j], z);
      mn[j] = fminf(mn[j], z);
      zs[j] += z;
      zq[j] = fmaf(z, z, zq[j]);
    }
  }
  #pragma unroll
  for (int j = 0; j < 32; j++) {
    mx[j] = fmaxf(mx[j], __shfl_xor(mx[j], 1, 64)); mx[j] = fmaxf(mx[j], __shfl_xor(mx[j], 2, 64));
    mn[j] = fminf(mn[j], __shfl_xor(mn[j], 1, 64)); mn[j] = fminf(mn[j], __shfl_xor(mn[j], 2, 64));
  }
  if (q == 0 && n < NN) {
    float4* om = reinterpret_cast<float4*>(mxb + (size_t)n * 32);
    float4* on = reinterpret_cast<float4*>(mnb + (size_t)n * 32);
    #pragma unroll
    for (int j = 0; j < 8; j++) {
      om[j] = make_float4(mx[4 * j], mx[4 * j + 1], mx[4 * j + 2], mx[4 * j + 3]);
      on[j] = make_float4(mn[4 * j], mn[4 * j + 1], mn[4 * j + 2], mn[4 * j + 3]);
    }
  }
  reduce64(zs, zq, red, gsum, gssq);
}

// BN finalize: a = g*rsqrt(var+eps), c = be - mu*a; zero sums for reuse
__global__ void k_finalize(float* __restrict__ sum, float* __restrict__ ssq,
                           const float* __restrict__ g, const float* __restrict__ be,
                           float inv_n, int ncols, float* __restrict__ a, float* __restrict__ c) {
  int j = threadIdx.x;
  if (j < ncols) {
    float mu = sum[j] * inv_n;
    float var = fmaxf(ssq[j] * inv_n - mu * mu, 0.f);
    float s = rsqrtf(var + 1e-5f) * g[j];
    a[j] = s; c[j] = be[j] - mu * s;
    sum[j] = 0.f; ssq[j] = 0.f;
  }
}

// ---------- fused agg-finalize + h_pre = [x, agg] @ w2a + b2a (+stats) ----------

__global__ __launch_bounds__(256) void k_hpre2(const float* __restrict__ xp,
    const float* __restrict__ mxb, const float* __restrict__ mnb, const int* __restrict__ starts,
    const float* __restrict__ A2, const float* __restrict__ C2, const float* __restrict__ w2aT,
    float* __restrict__ hpre, float* __restrict__ gsum, float* __restrict__ gssq) {
  __shared__ float red[256];
  const int n = blockIdx.x * 256 + threadIdx.x;
  float h[32], hh[32];
  #pragma unroll
  for (int j = 0; j < 32; j++) h[j] = 0.f;
  if (n < NN) {
    float xv[11];
    const float4* xr = reinterpret_cast<const float4*>(xp + (size_t)n * 12);
    float4 r0 = xr[0], r1 = xr[1], r2 = xr[2];
    xv[0]=r0.x; xv[1]=r0.y; xv[2]=r0.z; xv[3]=r0.w; xv[4]=r1.x; xv[5]=r1.y; xv[6]=r1.z; xv[7]=r1.w;
    xv[8]=r2.x; xv[9]=r2.y; xv[10]=r2.z;
    const int deg = starts[n + 1] - starts[n];
    float av[32];
    if (deg > 0) {
      #pragma unroll
      for (int j = 0; j < 32; j++) {
        float a = A2[j];
        float v = (a > 0.f) ? mxb[(size_t)n * 32 + j] : mnb[(size_t)n * 32 + j];
        av[j] = fmaxf(0.f, fmaf(a, v, C2[j]));
      }
    } else {
      #pragma unroll
      for (int j = 0; j < 32; j++) av[j] = 0.f;
    }
    #pragma unroll
    for (int j = 0; j < 32; j++) {
      const float* wr = w2aT + j * 44;  // uniform -> scalar loads
      float acc = wr[43];
      #pragma unroll
      for (int k = 0; k < 11; k++) acc = fmaf(xv[k], wr[k], acc);
      #pragma unroll
      for (int k = 0; k < 32; k++) acc = fmaf(av[k], wr[11 + k], acc);
      h[j] = acc;
    }
    float4* hp = reinterpret_cast<float4*>(hpre + (size_t)n * 32);
    #pragma unroll
    for (int j = 0; j < 8; j++)
      hp[j] = make_float4(h[4 * j], h[4 * j + 1], h[4 * j + 2], h[4 * j + 3]);
  }
  #pragma unroll
  for (int j = 0; j < 32; j++) hh[j] = h[j] * h[j];
  reduce64(h, hh, red, gsum, gssq);
}

// comb = relu(relu(bn(h_pre)) @ w2b + b2b) -> xp col 10
__global__ __launch_bounds__(256) void k_comb(const float* __restrict__ hpre,
    const float* __restrict__ a3, const float* __restrict__ c3,
    const float* __restrict__ w2b, const float* __restrict__ b2b, float* __restrict__ xp) {
  const int n = blockIdx.x * 256 + threadIdx.x;
  if (n >= NN) return;
  const float4* hp = reinterpret_cast<const float4*>(hpre + (size_t)n * 32);
  float acc = b2b[0];
  #pragma unroll
  for (int j = 0; j < 8; j++) {
    float4 v = hp[j];
    acc += fmaxf(0.f, fmaf(v.x, a3[4 * j],     c3[4 * j]))     * w2b[4 * j];
    acc += fmaxf(0.f, fmaf(v.y, a3[4 * j + 1], c3[4 * j + 1])) * w2b[4 * j + 1];
    acc += fmaxf(0.f, fmaf(v.z, a3[4 * j + 2], c3[4 * j + 2])) * w2b[4 * j + 2];
    acc += fmaxf(0.f, fmaf(v.w, a3[4 * j + 3], c3[4 * j + 3])) * w2b[4 * j + 3];
  }
  xp[(size_t)n * 12 + 10] = fmaxf(acc, 0.f);
}

// ---------- power MLP ----------

__global__ __launch_bounds__(256) void k_p5(const float* __restrict__ xp, const float* __restrict__ wpaT,
                                            float* __restrict__ gsum, float* __restrict__ gssq) {
  __shared__ float red[256];
  const int n = blockIdx.x * 256 + threadIdx.x;
  float y[32], yy[32];
  #pragma unroll
  for (int j = 0; j < 32; j++) y[j] = 0.f;
  if (n < NN) {
    float xv[11];
    const float4* xr = reinterpret_cast<const float4*>(xp + (size_t)n * 12);
    float4 r0 = xr[0], r1 = xr[1], r2 = xr[2];
    xv[0]=r0.x; xv[1]=r0.y; xv[2]=r0.z; xv[3]=r0.w; xv[4]=r1.x; xv[5]=r1.y; xv[6]=r1.z; xv[7]=r1.w;
    xv[8]=r2.x; xv[9]=r2.y; xv[10]=r2.z;
    #pragma unroll
    for (int j = 0; j < 32; j++) {
      const float* wr = wpaT + j * 12;
      float acc = wr[11];
      #pragma unroll
      for (int k = 0; k < 11; k++) acc = fmaf(xv[k], wr[k], acc);
      y[j] = acc;
    }
  }
  #pragma unroll
  for (int j = 0; j < 32; j++) yy[j] = y[j] * y[j];
  reduce64(y, yy, red, gsum, gssq);
}

__global__ __launch_bounds__(256) void k_p6(const float* __restrict__ xp, const float* __restrict__ wpaT,
    const float* __restrict__ a4, const float* __restrict__ c4,
    const float* __restrict__ wpb, const float* __restrict__ bpb,
    float* __restrict__ yq, float* __restrict__ gsum, float* __restrict__ gssq) {
  __shared__ float red[8];
  const int n = blockIdx.x * 256 + threadIdx.x;
  float sum = 0.f, ssq = 0.f;
  if (n < NN) {
    float xv[11];
    const float4* xr = reinterpret_cast<const float4*>(xp + (size_t)n * 12);
    float4 r0 = xr[0], r1 = xr[1], r2 = xr[2];
    xv[0]=r0.x; xv[1]=r0.y; xv[2]=r0.z; xv[3]=r0.w; xv[4]=r1.x; xv[5]=r1.y; xv[6]=r1.z; xv[7]=r1.w;
    xv[8]=r2.x; xv[9]=r2.y; xv[10]=r2.z;
    float q = bpb[0];
    #pragma unroll
    for (int j = 0; j < 32; j++) {
      const float* wr = wpaT + j * 12;
      float acc = wr[11];
      #pragma unroll
      for (int k = 0; k < 11; k++) acc = fmaf(xv[k], wr[k], acc);
      q = fmaf(fmaxf(0.f, fmaf(acc, a4[j], c4[j])), wpb[j], q);
    }
    yq[n] = q;
    sum = q; ssq = q * q;
  }
  float s = wsum(sum), qq = wsum(ssq);
  const int wid = threadIdx.x >> 6, lane = threadIdx.x & 63;
  if (lane == 0) { red[wid] = s; red[4 + wid] = qq; }
  __syncthreads();
  if (threadIdx.x == 0) {
    unsafeAtomicAdd(&gsum[0], red[0] + red[1] + red[2] + red[3]);
    unsafeAtomicAdd(&gssq[0], red[4] + red[5] + red[6] + red[7]);
  }
}

__global__ __launch_bounds__(256) void k_p7(const float* __restrict__ yq,
    const float* __restrict__ a5, const float* __restrict__ c5, float* __restrict__ out) {
  int n = blockIdx.x * 256 + threadIdx.x;
  if (n < NN) out[n] = fmaxf(0.f, fmaf(yq[n], a5[0], c5[0]));
}

// ---------- host launch ----------

extern "C" void kernel_launch(void* const* d_in, const int* in_sizes, int n_in,
                              void* d_out, int out_size, void* d_ws, size_t ws_size,
                              hipStream_t stream) {
  const float* x    = (const float*)d_in[0];
  const float* ea   = (const float*)d_in[1];
  const int*   ei   = (const int*)d_in[2];
  const int*   srcp = ei;
  const int*   dstp = ei + EE;
  const float* w1a = (const float*)d_in[3],  *b1a = (const float*)d_in[4];
  const float* g1a = (const float*)d_in[5],  *be1a = (const float*)d_in[6];
  const float* w1b = (const float*)d_in[7],  *b1b = (const float*)d_in[8];
  const float* g1b = (const float*)d_in[9],  *be1b = (const float*)d_in[10];
  const float* w2a = (const float*)d_in[11], *b2a = (const float*)d_in[12];
  const float* g2a = (const float*)d_in[13], *be2a = (const float*)d_in[14];
  const float* w2b = (const float*)d_in[15], *b2b = (const float*)d_in[16];
  const float* wpa = (const float*)d_in[17], *bpa = (const float*)d_in[18];
  const float* gpa = (const float*)d_in[19], *bepa = (const float*)d_in[20];
  const float* wpb = (const float*)d_in[21], *bpb = (const float*)d_in[22];
  const float* gpb = (const float*)d_in[23], *bepb = (const float*)d_in[24];

  size_t off = 0;
  char* base = (char*)d_ws;
  auto alloc = [&](size_t bytes) -> void* {
    void* p = base + off;
    off += (bytes + 255) & ~(size_t)255;
    return p;
  };
  float* stats = (float*)alloc(2048);
  float* coef  = (float*)alloc(2048);
  float* mom   = (float*)alloc(512);               // 99 used, 128 zeroed
  float* cmom  = (float*)alloc(256);               // 5 used
  float* w1f   = (float*)alloc(16 * 32 * 4);
  float* w2t   = (float*)alloc(32 * 32 * 4);
  float* w2aT  = (float*)alloc(32 * 44 * 4);
  float* wpaT  = (float*)alloc(32 * 12 * 4);
  int*   cnt    = (int*)alloc(NN * 4);
  int*   deg    = (int*)alloc(NN * 4);
  float* sea    = (float*)alloc((size_t)NN * 2 * 4);
  int*   starts = (int*)alloc((NN + 1) * 4);
  int*   fill   = (int*)alloc(NN * 4);
  int*   srcc   = (int*)alloc((size_t)EE * 4);
  float* eac    = (float*)alloc((size_t)EE * 2 * 4);
  float* xp     = (float*)alloc((size_t)NN * 12 * 4);
  float* mxb    = (float*)alloc((size_t)NN * 32 * 4);
  float* mnb    = (float*)alloc((size_t)NN * 32 * 4);
  float* hpre   = (float*)alloc((size_t)NN * 32 * 4);
  float* yq     = (float*)alloc(NN * 4);

  float *SUM2 = stats,       *SSQ2 = stats + 32;
  float *SUM3 = stats + 64,  *SSQ3 = stats + 96;
  float *SUM4 = stats + 128, *SSQ4 = stats + 160;
  float *SUM5 = stats + 192, *SSQ5 = stats + 224;
  float *A2 = coef,       *C2 = coef + 32;
  float *A3 = coef + 64,  *C3 = coef + 96;
  float *A4 = coef + 128, *C4 = coef + 160;
  float *A5 = coef + 192, *C5 = coef + 224;

  hipMemsetAsync(stats, 0, 2048, stream);
  hipMemsetAsync(mom, 0, 512 + 256, stream);       // mom + cmom (contiguous allocs, both 256-aligned)
  hipMemsetAsync(cnt, 0, NN * 4, stream);
  hipMemsetAsync(deg, 0, NN * 4, stream);
  hipMemsetAsync(sea, 0, (size_t)NN * 2 * 4, stream);

  const int GN = (NN + 255) / 256;        // 391
  const int GA = (4 * NN + 255) / 256;    // 1563
  const int GE = 2048;

  k_wprep  <<<1, 256, 0, stream>>>(w1b, w2a, b2a, wpa, bpa, w2t, w2aT, wpaT);
  k_prep   <<<GE, 256, 0, stream>>>(dstp, srcp, (const float2*)ea, cnt, deg, sea, cmom);
  k_scan   <<<1, 1024, 0, stream>>>(cnt, starts, fill);
  k_scatter<<<GE, 256, 0, stream>>>(dstp, srcp, (const float2*)ea, fill, srcc, (float2*)eac);
  k_xp     <<<GN, 256, 0, stream>>>(x, xp);

  const float invE = 1.f / EF, invN = 1.f / (float)NN;
  for (int c = 0; c < 3; c++) {
    k_mom     <<<GN, 256, 0, stream>>>(xp, deg, sea, mom);
    k_fin1    <<<1, 32, 0, stream>>>(mom, cmom, w1a, b1a, g1a, be1a, w1f);
    k_fusedagg<<<GA, 256, 0, stream>>>(starts, srcc, (const float2*)eac, xp, w1f, w2t, b1b,
                                       mxb, mnb, SUM2, SSQ2);
    k_finalize<<<1, 32, 0, stream>>>(SUM2, SSQ2, g1b, be1b, invE, 32, A2, C2);
    k_hpre2   <<<GN, 256, 0, stream>>>(xp, mxb, mnb, starts, A2, C2, w2aT, hpre, SUM3, SSQ3);
    k_finalize<<<1, 32, 0, stream>>>(SUM3, SSQ3, g2a, be2a, invN, 32, A3, C3);
    k_comb    <<<GN, 256, 0, stream>>>(hpre, A3, C3, w2b, b2b, xp);
  }

  k_p5      <<<GN, 256, 0, stream>>>(xp, wpaT, SUM4, SSQ4);
  k_finalize<<<1, 32, 0, stream>>>(SUM4, SSQ4, gpa, bepa, invN, 32, A4, C4);
  k_p6      <<<GN, 256, 0, stream>>>(xp, wpaT, A4, C4, wpb, bpb, yq, SUM5, SSQ5);
  k_finalize<<<1, 32, 0, stream>>>(SUM5, SSQ5, gpb, bepb, invN, 1, A5, C5);
  k_p7      <<<GN, 256, 0, stream>>>(yq, A5, C5, (float*)d_out);
}